// Round 2
// baseline (702.176 us; speedup 1.0000x reference)
//
#include <hip/hip_runtime.h>
#include <math.h>

#define NN 50000
#define NE 800000
#define HH 4
#define DD 32
#define CC 128   // H*D == IN_FEATS == 128

// ---------------- init m = -inf ----------------
__global__ __launch_bounds__(256) void k_init_m(float* __restrict__ m, int n) {
    int i = blockIdx.x * 256 + threadIdx.x;
    if (i < n) m[i] = -INFINITY;
}

// ---------------- GEMM: ft[n,o] = sum_k feat[n,k] * W[o,k] ----------------
// W is [128 out][128 in] row-major. Stage W transposed in LDS (padded),
// 32 feat rows per block, each thread computes 2 rows x 8 cols.
__global__ __launch_bounds__(256) void k_gemm(const float* __restrict__ feat,
                                              const float* __restrict__ W,
                                              float* __restrict__ ft, int N) {
    __shared__ float Wt[128][136];  // Wt[k][o] = W[o][k]
    __shared__ float fs[32][129];   // pad -> conflict-free broadcast reads

    // load W transposed (coalesced global reads, padded LDS writes)
    for (int i = threadIdx.x; i < 128 * 128; i += 256) {
        int o = i >> 7, k = i & 127;
        Wt[k][o] = W[i];
    }
    int row0 = blockIdx.x * 32;
    for (int i = threadIdx.x; i < 32 * 128; i += 256) {
        int r = i >> 7, k = i & 127;
        int gr = row0 + r;
        fs[r][k] = (gr < N) ? feat[gr * 128 + k] : 0.f;
    }
    __syncthreads();

    int r0 = threadIdx.x >> 4;          // 0..15 (second row = r0+16)
    int c0 = (threadIdx.x & 15) * 8;    // 0..120
    float acc0[8] = {0, 0, 0, 0, 0, 0, 0, 0};
    float acc1[8] = {0, 0, 0, 0, 0, 0, 0, 0};
    for (int k = 0; k < 128; ++k) {
        float f0 = fs[r0][k];
        float f1 = fs[r0 + 16][k];
#pragma unroll
        for (int j = 0; j < 8; ++j) {
            float w = Wt[k][c0 + j];
            acc0[j] += f0 * w;
            acc1[j] += f1 * w;
        }
    }
    int g0 = row0 + r0, g1 = row0 + r0 + 16;
    if (g0 < N) {
#pragma unroll
        for (int j = 0; j < 8; ++j) ft[g0 * 128 + c0 + j] = acc0[j];
    }
    if (g1 < N) {
#pragma unroll
        for (int j = 0; j < 8; ++j) ft[g1 * 128 + c0 + j] = acc1[j];
    }
}

// float atomic max via int punning (valid with -inf init)
__device__ __forceinline__ void atomicMaxF(float* addr, float val) {
    if (val >= 0.f) {
        atomicMax((int*)addr, __float_as_int(val));
    } else {
        atomicMin((unsigned int*)addr, (unsigned int)__float_as_int(val));
    }
}

// ---------------- per-edge, per-head dot + segment max ----------------
__global__ __launch_bounds__(256) void k_edge_dot(const float4* __restrict__ ft4,
                                                  const int* __restrict__ src,
                                                  const int* __restrict__ dst,
                                                  float* __restrict__ a,
                                                  float* __restrict__ m) {
    int idx = blockIdx.x * 256 + threadIdx.x;
    if (idx >= NE * HH) return;
    int e = idx >> 2, h = idx & 3;
    int sn = src[e], dn = dst[e];
    const float4* pa = ft4 + (size_t)sn * 32 + h * 8;
    const float4* pb = ft4 + (size_t)dn * 32 + h * 8;
    float acc = 0.f;
#pragma unroll
    for (int i = 0; i < 8; ++i) {
        float4 x = pa[i];
        float4 y = pb[i];
        acc += x.x * y.x + x.y * y.y + x.z * y.z + x.w * y.w;
    }
    acc *= 0.17677669529663687f;  // 1/sqrt(32)
    a[idx] = acc;
    atomicMaxF(&m[dn * 4 + h], acc);
}

// ---------------- e = exp(a - m[dst]); s[dst] += e ----------------
__global__ __launch_bounds__(256) void k_expsum(float* __restrict__ a,
                                                const int* __restrict__ dst,
                                                const float* __restrict__ m,
                                                float* __restrict__ sden) {
    int idx = blockIdx.x * 256 + threadIdx.x;
    if (idx >= NE * HH) return;
    int e = idx >> 2, h = idx & 3;
    int dn = dst[e];
    float v = __expf(a[idx] - m[dn * 4 + h]);
    a[idx] = v;
    atomicAdd(&sden[dn * 4 + h], v);
}

// ---------------- out[dst,c] += ft[src,c] * e/s ----------------
// 128 threads per edge (c = h*32+d), 2 edges per block.
__global__ __launch_bounds__(256) void k_scatter(const float* __restrict__ ft,
                                                 const float* __restrict__ a,
                                                 const float* __restrict__ sden,
                                                 const int* __restrict__ src,
                                                 const int* __restrict__ dst,
                                                 float* __restrict__ out) {
    int idx = blockIdx.x * 256 + threadIdx.x;  // < NE*128 = 102.4M
    int e = idx >> 7;
    int c = idx & 127;
    int h = c >> 5;
    int sn = src[e], dn = dst[e];
    float w = a[e * 4 + h] / sden[dn * 4 + h];
    atomicAdd(&out[dn * 128 + c], ft[sn * 128 + c] * w);
}

extern "C" void kernel_launch(void* const* d_in, const int* in_sizes, int n_in,
                              void* d_out, int out_size, void* d_ws, size_t ws_size,
                              hipStream_t stream) {
    const float* feat = (const float*)d_in[0];
    const float* W    = (const float*)d_in[1];
    const int*   src  = (const int*)d_in[2];
    const int*   dst  = (const int*)d_in[3];
    float* out = (float*)d_out;

    // workspace layout (floats)
    float* ft   = (float*)d_ws;                 // NN*128 = 6.4M
    float* a    = ft + (size_t)NN * 128;        // NE*4   = 3.2M
    float* m    = a  + (size_t)NE * 4;          // NN*4   = 0.2M
    float* sden = m  + (size_t)NN * 4;          // NN*4   = 0.2M

    hipMemsetAsync(out, 0, (size_t)NN * 128 * sizeof(float), stream);
    hipMemsetAsync(sden, 0, (size_t)NN * 4 * sizeof(float), stream);
    k_init_m<<<(NN * 4 + 255) / 256, 256, 0, stream>>>(m, NN * 4);

    k_gemm<<<(NN + 31) / 32, 256, 0, stream>>>(feat, W, ft, NN);
    k_edge_dot<<<(NE * 4 + 255) / 256, 256, 0, stream>>>((const float4*)ft, src, dst, a, m);
    k_expsum<<<(NE * 4 + 255) / 256, 256, 0, stream>>>(a, dst, m, sden);
    k_scatter<<<(NE * 128) / 256, 256, 0, stream>>>(ft, a, sden, src, dst, out);
}

// Round 3
// 551.825 us; speedup vs baseline: 1.2725x; 1.2725x over previous
//
#include <hip/hip_runtime.h>
#include <math.h>

#define NN 50000
#define NE 800000
#define HH 4
#define DD 32

// ---------------- GEMM: ft[n,o] = sum_k feat[n,k] * W[o,k] ----------------
__global__ __launch_bounds__(256) void k_gemm(const float* __restrict__ feat,
                                              const float* __restrict__ W,
                                              float* __restrict__ ft, int N) {
    __shared__ float Wt[128][136];  // Wt[k][o] = W[o][k]
    __shared__ float fs[32][129];

    for (int i = threadIdx.x; i < 128 * 128; i += 256) {
        int o = i >> 7, k = i & 127;
        Wt[k][o] = W[i];
    }
    int row0 = blockIdx.x * 32;
    for (int i = threadIdx.x; i < 32 * 128; i += 256) {
        int r = i >> 7, k = i & 127;
        int gr = row0 + r;
        fs[r][k] = (gr < N) ? feat[gr * 128 + k] : 0.f;
    }
    __syncthreads();

    int r0 = threadIdx.x >> 4;
    int c0 = (threadIdx.x & 15) * 8;
    float acc0[8] = {0, 0, 0, 0, 0, 0, 0, 0};
    float acc1[8] = {0, 0, 0, 0, 0, 0, 0, 0};
    for (int k = 0; k < 128; ++k) {
        float f0 = fs[r0][k];
        float f1 = fs[r0 + 16][k];
#pragma unroll
        for (int j = 0; j < 8; ++j) {
            float w = Wt[k][c0 + j];
            acc0[j] += f0 * w;
            acc1[j] += f1 * w;
        }
    }
    int g0 = row0 + r0, g1 = row0 + r0 + 16;
    if (g0 < N) {
#pragma unroll
        for (int j = 0; j < 8; ++j) ft[g0 * 128 + c0 + j] = acc0[j];
    }
    if (g1 < N) {
#pragma unroll
        for (int j = 0; j < 8; ++j) ft[g1 * 128 + c0 + j] = acc1[j];
    }
}

// ---------------- CSR build ----------------
__global__ __launch_bounds__(256) void k_hist(const int* __restrict__ dst, int* __restrict__ cnt) {
    int e = blockIdx.x * 256 + threadIdx.x;
    if (e < NE) atomicAdd(&cnt[dst[e]], 1);
}

__global__ __launch_bounds__(256) void k_scan1(const int* __restrict__ cnt, int* __restrict__ row,
                                               int* __restrict__ partial, int n) {
    __shared__ int sh[256];
    int i = blockIdx.x * 256 + threadIdx.x;
    int x = (i < n) ? cnt[i] : 0;
    sh[threadIdx.x] = x;
    __syncthreads();
    for (int off = 1; off < 256; off <<= 1) {
        int v = (threadIdx.x >= off) ? sh[threadIdx.x - off] : 0;
        __syncthreads();
        sh[threadIdx.x] += v;
        __syncthreads();
    }
    if (i < n) row[i] = sh[threadIdx.x] - x;  // exclusive
    if (threadIdx.x == 255) partial[blockIdx.x] = sh[255];
}

__global__ __launch_bounds__(256) void k_scan2(int* __restrict__ partial, int nb) {
    __shared__ int sh[256];
    int t = threadIdx.x;
    int x = (t < nb) ? partial[t] : 0;
    sh[t] = x;
    __syncthreads();
    for (int off = 1; off < 256; off <<= 1) {
        int v = (t >= off) ? sh[t - off] : 0;
        __syncthreads();
        sh[t] += v;
        __syncthreads();
    }
    if (t < nb) partial[t] = sh[t] - x;  // exclusive block offsets
}

__global__ __launch_bounds__(256) void k_scan3(int* __restrict__ row, int* __restrict__ cur,
                                               const int* __restrict__ partial, int n) {
    int i = blockIdx.x * 256 + threadIdx.x;
    if (i < n) {
        int val = row[i] + partial[blockIdx.x];
        row[i] = val;
        cur[i] = val;
    }
    if (i == 0) row[n] = NE;
}

__global__ __launch_bounds__(256) void k_fill(const int* __restrict__ src, const int* __restrict__ dst,
                                              int* __restrict__ cur, int* __restrict__ srcs,
                                              int* __restrict__ pos) {
    int e = blockIdx.x * 256 + threadIdx.x;
    if (e >= NE) return;
    int p = atomicAdd(&cur[dst[e]], 1);
    srcs[p] = src[e];
    pos[e] = p;
}

// ---------------- per-edge, per-head dot, written in CSR order ----------------
__global__ __launch_bounds__(256) void k_edge_dot(const float4* __restrict__ ft4,
                                                  const int* __restrict__ src,
                                                  const int* __restrict__ dst,
                                                  const int* __restrict__ pos,
                                                  float* __restrict__ a) {
    int idx = blockIdx.x * 256 + threadIdx.x;
    if (idx >= NE * HH) return;
    int e = idx >> 2, h = idx & 3;
    int sn = src[e], dn = dst[e];
    const float4* pa = ft4 + (size_t)sn * 32 + h * 8;
    const float4* pb = ft4 + (size_t)dn * 32 + h * 8;
    float acc = 0.f;
#pragma unroll
    for (int i = 0; i < 8; ++i) {
        float4 x = pa[i];
        float4 y = pb[i];
        acc += x.x * y.x + x.y * y.y + x.z * y.z + x.w * y.w;
    }
    acc *= 0.17677669529663687f;  // 1/sqrt(32)
    a[pos[e] * 4 + h] = acc;
}

// ---------------- per-node fused softmax + aggregate ----------------
// one block (128 threads) per dst node; thread c = h*32+d owns out[n,c]
__global__ __launch_bounds__(128) void k_agg(const float* __restrict__ ft,
                                             const float* __restrict__ a,
                                             const int* __restrict__ row,
                                             const int* __restrict__ srcs,
                                             float* __restrict__ out) {
    int n = blockIdx.x;
    int c = threadIdx.x;
    int h = c >> 5;
    int r0 = row[n], r1 = row[n + 1];
    if (r0 == r1) {
        out[(size_t)n * 128 + c] = 0.f;
        return;
    }
    float mx = -INFINITY;
    for (int p = r0; p < r1; ++p) {
        float v = a[p * 4 + h];
        mx = fmaxf(mx, v);
    }
    float s = 0.f, acc = 0.f;
    for (int p = r0; p < r1; ++p) {
        float w = __expf(a[p * 4 + h] - mx);
        s += w;
        acc += ft[(size_t)srcs[p] * 128 + c] * w;
    }
    out[(size_t)n * 128 + c] = acc / s;
}

extern "C" void kernel_launch(void* const* d_in, const int* in_sizes, int n_in,
                              void* d_out, int out_size, void* d_ws, size_t ws_size,
                              hipStream_t stream) {
    const float* feat = (const float*)d_in[0];
    const float* W    = (const float*)d_in[1];
    const int*   src  = (const int*)d_in[2];
    const int*   dst  = (const int*)d_in[3];
    float* out = (float*)d_out;

    // workspace layout (4-byte units)
    float* ft     = (float*)d_ws;                        // 6,400,000
    float* a      = ft + (size_t)NN * 128;               // 3,200,000
    int*   row    = (int*)(a + (size_t)NE * 4);          // 50,001
    int*   cur    = row + (NN + 1);                      // 50,000
    int*   srcs   = cur + NN;                            // 800,000
    int*   pos    = srcs + NE;                           // 800,000
    int*   cnt    = pos + NE;                            // 50,000
    int*   part   = cnt + NN;                            // 256

    const int NB1 = (NN + 255) / 256;  // 196

    hipMemsetAsync(cnt, 0, (size_t)NN * sizeof(int), stream);
    k_hist<<<(NE + 255) / 256, 256, 0, stream>>>(dst, cnt);
    k_scan1<<<NB1, 256, 0, stream>>>(cnt, row, part, NN);
    k_scan2<<<1, 256, 0, stream>>>(part, NB1);
    k_scan3<<<NB1, 256, 0, stream>>>(row, cur, part, NN);
    k_fill<<<(NE + 255) / 256, 256, 0, stream>>>(src, dst, cur, srcs, pos);

    k_gemm<<<(NN + 31) / 32, 256, 0, stream>>>(feat, W, ft, NN);
    k_edge_dot<<<(NE * 4 + 255) / 256, 256, 0, stream>>>((const float4*)ft, src, dst, pos, a);
    k_agg<<<NN, 128, 0, stream>>>(ft, a, row, srcs, out);
}

// Round 4
// 381.328 us; speedup vs baseline: 1.8414x; 1.4471x over previous
//
#include <hip/hip_runtime.h>
#include <math.h>

#define NN 50000
#define NE 800000
#define HH 4
#define DD 32

// ---------------- GEMM: ft[n,o] = sum_k feat[n,k] * W[o,k] ----------------
__global__ __launch_bounds__(256) void k_gemm(const float* __restrict__ feat,
                                              const float* __restrict__ W,
                                              float* __restrict__ ft, int N) {
    __shared__ float Wt[128][136];  // Wt[k][o] = W[o][k]
    __shared__ float fs[32][129];

    for (int i = threadIdx.x; i < 128 * 128; i += 256) {
        int o = i >> 7, k = i & 127;
        Wt[k][o] = W[i];
    }
    int row0 = blockIdx.x * 32;
    for (int i = threadIdx.x; i < 32 * 128; i += 256) {
        int r = i >> 7, k = i & 127;
        int gr = row0 + r;
        fs[r][k] = (gr < N) ? feat[gr * 128 + k] : 0.f;
    }
    __syncthreads();

    int r0 = threadIdx.x >> 4;
    int c0 = (threadIdx.x & 15) * 8;
    float acc0[8] = {0, 0, 0, 0, 0, 0, 0, 0};
    float acc1[8] = {0, 0, 0, 0, 0, 0, 0, 0};
    for (int k = 0; k < 128; ++k) {
        float f0 = fs[r0][k];
        float f1 = fs[r0 + 16][k];
#pragma unroll
        for (int j = 0; j < 8; ++j) {
            float w = Wt[k][c0 + j];
            acc0[j] += f0 * w;
            acc1[j] += f1 * w;
        }
    }
    int g0 = row0 + r0, g1 = row0 + r0 + 16;
    if (g0 < N) {
#pragma unroll
        for (int j = 0; j < 8; ++j) ft[g0 * 128 + c0 + j] = acc0[j];
    }
    if (g1 < N) {
#pragma unroll
        for (int j = 0; j < 8; ++j) ft[g1 * 128 + c0 + j] = acc1[j];
    }
}

// ---------------- CSR build ----------------
__global__ __launch_bounds__(256) void k_hist(const int* __restrict__ dst, int* __restrict__ cnt) {
    int e = blockIdx.x * 256 + threadIdx.x;
    if (e < NE) atomicAdd(&cnt[dst[e]], 1);
}

__global__ __launch_bounds__(256) void k_scan1(const int* __restrict__ cnt, int* __restrict__ row,
                                               int* __restrict__ partial, int n) {
    __shared__ int sh[256];
    int i = blockIdx.x * 256 + threadIdx.x;
    int x = (i < n) ? cnt[i] : 0;
    sh[threadIdx.x] = x;
    __syncthreads();
    for (int off = 1; off < 256; off <<= 1) {
        int v = (threadIdx.x >= off) ? sh[threadIdx.x - off] : 0;
        __syncthreads();
        sh[threadIdx.x] += v;
        __syncthreads();
    }
    if (i < n) row[i] = sh[threadIdx.x] - x;  // exclusive
    if (threadIdx.x == 255) partial[blockIdx.x] = sh[255];
}

__global__ __launch_bounds__(256) void k_scan2(int* __restrict__ partial, int nb) {
    __shared__ int sh[256];
    int t = threadIdx.x;
    int x = (t < nb) ? partial[t] : 0;
    sh[t] = x;
    __syncthreads();
    for (int off = 1; off < 256; off <<= 1) {
        int v = (t >= off) ? sh[t - off] : 0;
        __syncthreads();
        sh[t] += v;
        __syncthreads();
    }
    if (t < nb) partial[t] = sh[t] - x;  // exclusive block offsets
}

__global__ __launch_bounds__(256) void k_scan3(int* __restrict__ row, int* __restrict__ cur,
                                               const int* __restrict__ partial, int n) {
    int i = blockIdx.x * 256 + threadIdx.x;
    if (i < n) {
        int val = row[i] + partial[blockIdx.x];
        row[i] = val;
        cur[i] = val;
    }
    if (i == 0) row[n] = NE;
}

__global__ __launch_bounds__(256) void k_fill(const int* __restrict__ src, const int* __restrict__ dst,
                                              int* __restrict__ cur, int* __restrict__ srcs) {
    int e = blockIdx.x * 256 + threadIdx.x;
    if (e >= NE) return;
    int p = atomicAdd(&cur[dst[e]], 1);
    srcs[p] = src[e];
}

// ---------------- fused edge-dot + online softmax + aggregate ----------------
// one block (128 threads) per dst node; thread c = h*32+d owns out[n,c].
// For each incident edge: gather ft[src] row once; per-head dot via shfl_xor
// within the 32-lane head group; online-softmax update of (m, s, acc).
__global__ __launch_bounds__(128) void k_agg(const float* __restrict__ ft,
                                             const int* __restrict__ row,
                                             const int* __restrict__ srcs,
                                             float* __restrict__ out) {
    int n = blockIdx.x;
    int c = threadIdx.x;
    int r0 = row[n], r1 = row[n + 1];
    size_t base = (size_t)n * 128 + c;
    float fd = ft[base];  // dst feature, loaded once per node
    float m = -INFINITY, s = 0.f, acc = 0.f;
    for (int p = r0; p < r1; ++p) {
        int sn = srcs[p];
        float fs = ft[(size_t)sn * 128 + c];
        float v = fd * fs;
        // reduce over the 32 lanes of this head group (masks < 32 never cross)
        v += __shfl_xor(v, 1);
        v += __shfl_xor(v, 2);
        v += __shfl_xor(v, 4);
        v += __shfl_xor(v, 8);
        v += __shfl_xor(v, 16);
        v *= 0.17677669529663687f;  // 1/sqrt(32)
        float mn = fmaxf(m, v);
        float sc = __expf(m - mn);   // 1 if max unchanged; 0 on first edge (m=-inf)
        float w  = __expf(v - mn);
        s   = s   * sc + w;
        acc = acc * sc + w * fs;
        m = mn;
    }
    out[base] = (r1 > r0) ? acc / s : 0.f;
}

extern "C" void kernel_launch(void* const* d_in, const int* in_sizes, int n_in,
                              void* d_out, int out_size, void* d_ws, size_t ws_size,
                              hipStream_t stream) {
    const float* feat = (const float*)d_in[0];
    const float* W    = (const float*)d_in[1];
    const int*   src  = (const int*)d_in[2];
    const int*   dst  = (const int*)d_in[3];
    float* out = (float*)d_out;

    // workspace layout (4-byte units)
    float* ft   = (float*)d_ws;                 // 6,400,000
    int*   row  = (int*)(ft + (size_t)NN * 128);// 50,001
    int*   cur  = row + (NN + 1);               // 50,000
    int*   srcs = cur + NN;                     // 800,000
    int*   cnt  = srcs + NE;                    // 50,000
    int*   part = cnt + NN;                     // 256

    const int NB1 = (NN + 255) / 256;  // 196

    hipMemsetAsync(cnt, 0, (size_t)NN * sizeof(int), stream);
    k_hist<<<(NE + 255) / 256, 256, 0, stream>>>(dst, cnt);
    k_scan1<<<NB1, 256, 0, stream>>>(cnt, row, part, NN);
    k_scan2<<<1, 256, 0, stream>>>(part, NB1);
    k_scan3<<<NB1, 256, 0, stream>>>(row, cur, part, NN);
    k_fill<<<(NE + 255) / 256, 256, 0, stream>>>(src, dst, cur, srcs);

    k_gemm<<<(NN + 31) / 32, 256, 0, stream>>>(feat, W, ft, NN);
    k_agg<<<NN, 128, 0, stream>>>(ft, row, srcs, out);
}

// Round 5
// 334.394 us; speedup vs baseline: 2.0998x; 1.1404x over previous
//
#include <hip/hip_runtime.h>
#include <math.h>

#define NN 50000
#define NE 800000
#define HH 4
#define DD 32

// ---------------- GEMM: ft[n,o] = sum_k feat[n,k] * W[o,k] ----------------
__global__ __launch_bounds__(256) void k_gemm(const float* __restrict__ feat,
                                              const float* __restrict__ W,
                                              float* __restrict__ ft, int N) {
    __shared__ float Wt[128][136];  // Wt[k][o] = W[o][k]
    __shared__ float fs[32][129];

    for (int i = threadIdx.x; i < 128 * 128; i += 256) {
        int o = i >> 7, k = i & 127;
        Wt[k][o] = W[i];
    }
    int row0 = blockIdx.x * 32;
    for (int i = threadIdx.x; i < 32 * 128; i += 256) {
        int r = i >> 7, k = i & 127;
        int gr = row0 + r;
        fs[r][k] = (gr < N) ? feat[gr * 128 + k] : 0.f;
    }
    __syncthreads();

    int r0 = threadIdx.x >> 4;
    int c0 = (threadIdx.x & 15) * 8;
    float acc0[8] = {0, 0, 0, 0, 0, 0, 0, 0};
    float acc1[8] = {0, 0, 0, 0, 0, 0, 0, 0};
    for (int k = 0; k < 128; ++k) {
        float f0 = fs[r0][k];
        float f1 = fs[r0 + 16][k];
#pragma unroll
        for (int j = 0; j < 8; ++j) {
            float w = Wt[k][c0 + j];
            acc0[j] += f0 * w;
            acc1[j] += f1 * w;
        }
    }
    int g0 = row0 + r0, g1 = row0 + r0 + 16;
    if (g0 < N) {
#pragma unroll
        for (int j = 0; j < 8; ++j) ft[g0 * 128 + c0 + j] = acc0[j];
    }
    if (g1 < N) {
#pragma unroll
        for (int j = 0; j < 8; ++j) ft[g1 * 128 + c0 + j] = acc1[j];
    }
}

// ---------------- CSR build ----------------
__global__ __launch_bounds__(256) void k_hist(const int* __restrict__ dst, int* __restrict__ cnt) {
    int e = blockIdx.x * 256 + threadIdx.x;
    if (e < NE) atomicAdd(&cnt[dst[e]], 1);
}

__global__ __launch_bounds__(256) void k_scan1(const int* __restrict__ cnt, int* __restrict__ row,
                                               int* __restrict__ partial, int n) {
    __shared__ int sh[256];
    int i = blockIdx.x * 256 + threadIdx.x;
    int x = (i < n) ? cnt[i] : 0;
    sh[threadIdx.x] = x;
    __syncthreads();
    for (int off = 1; off < 256; off <<= 1) {
        int v = (threadIdx.x >= off) ? sh[threadIdx.x - off] : 0;
        __syncthreads();
        sh[threadIdx.x] += v;
        __syncthreads();
    }
    if (i < n) row[i] = sh[threadIdx.x] - x;  // exclusive
    if (threadIdx.x == 255) partial[blockIdx.x] = sh[255];
}

__global__ __launch_bounds__(256) void k_scan2(int* __restrict__ partial, int nb) {
    __shared__ int sh[256];
    int t = threadIdx.x;
    int x = (t < nb) ? partial[t] : 0;
    sh[t] = x;
    __syncthreads();
    for (int off = 1; off < 256; off <<= 1) {
        int v = (t >= off) ? sh[t - off] : 0;
        __syncthreads();
        sh[t] += v;
        __syncthreads();
    }
    if (t < nb) partial[t] = sh[t] - x;  // exclusive block offsets
}

__global__ __launch_bounds__(256) void k_scan3(int* __restrict__ row, int* __restrict__ cur,
                                               const int* __restrict__ partial, int n) {
    int i = blockIdx.x * 256 + threadIdx.x;
    if (i < n) {
        int val = row[i] + partial[blockIdx.x];
        row[i] = val;
        cur[i] = val;
    }
    if (i == 0) row[n] = NE;
}

__global__ __launch_bounds__(256) void k_fill(const int* __restrict__ src, const int* __restrict__ dst,
                                              int* __restrict__ cur, int* __restrict__ srcs) {
    int e = blockIdx.x * 256 + threadIdx.x;
    if (e >= NE) return;
    int p = atomicAdd(&cur[dst[e]], 1);
    srcs[p] = src[e];
}

// ---------------- fused edge-dot + online softmax + aggregate ----------------
// one WAVE (64 lanes) per dst node; lane l owns channels 2l,2l+1 (float2).
// Head group = 16 lanes; per-head dot via 4x shfl_xor. Edges processed in
// pairs: two independent shuffle chains (ILP) + single online rescale/pair.
__global__ __launch_bounds__(256) void k_agg(const float2* __restrict__ ft2,
                                             const int* __restrict__ row,
                                             const int* __restrict__ srcs,
                                             float2* __restrict__ out2) {
    int n = blockIdx.x * 4 + (threadIdx.x >> 6);
    int l = threadIdx.x & 63;
    int r0 = row[n], r1 = row[n + 1];
    size_t base = (size_t)n * 64 + l;
    float2 fd = ft2[base];  // dst row, loaded once
    float m = -INFINITY, s = 0.f;
    float ax = 0.f, ay = 0.f;
    int p = r0;
    for (; p + 1 < r1; p += 2) {
        int s0 = srcs[p], s1 = srcs[p + 1];
        float2 f0 = ft2[(size_t)s0 * 64 + l];
        float2 f1 = ft2[(size_t)s1 * 64 + l];
        float v0 = fd.x * f0.x + fd.y * f0.y;
        float v1 = fd.x * f1.x + fd.y * f1.y;
        v0 += __shfl_xor(v0, 1);  v1 += __shfl_xor(v1, 1);
        v0 += __shfl_xor(v0, 2);  v1 += __shfl_xor(v1, 2);
        v0 += __shfl_xor(v0, 4);  v1 += __shfl_xor(v1, 4);
        v0 += __shfl_xor(v0, 8);  v1 += __shfl_xor(v1, 8);
        v0 *= 0.17677669529663687f;  // 1/sqrt(32)
        v1 *= 0.17677669529663687f;
        float mn = fmaxf(fmaxf(m, v0), v1);  // v_max3
        float sc = __expf(m - mn);           // 0 on first pair (m=-inf)
        float w0 = __expf(v0 - mn);
        float w1 = __expf(v1 - mn);
        s = s * sc + w0 + w1;
        ax = ax * sc + w0 * f0.x + w1 * f1.x;
        ay = ay * sc + w0 * f0.y + w1 * f1.y;
        m = mn;
    }
    if (p < r1) {  // odd tail
        int s0 = srcs[p];
        float2 f0 = ft2[(size_t)s0 * 64 + l];
        float v0 = fd.x * f0.x + fd.y * f0.y;
        v0 += __shfl_xor(v0, 1);
        v0 += __shfl_xor(v0, 2);
        v0 += __shfl_xor(v0, 4);
        v0 += __shfl_xor(v0, 8);
        v0 *= 0.17677669529663687f;
        float mn = fmaxf(m, v0);
        float sc = __expf(m - mn);
        float w0 = __expf(v0 - mn);
        s = s * sc + w0;
        ax = ax * sc + w0 * f0.x;
        ay = ay * sc + w0 * f0.y;
    }
    float inv = (r1 > r0) ? 1.f / s : 0.f;
    out2[base] = make_float2(ax * inv, ay * inv);
}

extern "C" void kernel_launch(void* const* d_in, const int* in_sizes, int n_in,
                              void* d_out, int out_size, void* d_ws, size_t ws_size,
                              hipStream_t stream) {
    const float* feat = (const float*)d_in[0];
    const float* W    = (const float*)d_in[1];
    const int*   src  = (const int*)d_in[2];
    const int*   dst  = (const int*)d_in[3];
    float* out = (float*)d_out;

    // workspace layout (4-byte units)
    float* ft   = (float*)d_ws;                 // 6,400,000
    int*   row  = (int*)(ft + (size_t)NN * 128);// 50,001
    int*   cur  = row + (NN + 1);               // 50,000
    int*   srcs = cur + NN;                     // 800,000
    int*   cnt  = srcs + NE;                    // 50,000
    int*   part = cnt + NN;                     // 256

    const int NB1 = (NN + 255) / 256;  // 196

    hipMemsetAsync(cnt, 0, (size_t)NN * sizeof(int), stream);
    k_hist<<<(NE + 255) / 256, 256, 0, stream>>>(dst, cnt);
    k_scan1<<<NB1, 256, 0, stream>>>(cnt, row, part, NN);
    k_scan2<<<1, 256, 0, stream>>>(part, NB1);
    k_scan3<<<NB1, 256, 0, stream>>>(row, cur, part, NN);
    k_fill<<<(NE + 255) / 256, 256, 0, stream>>>(src, dst, cur, srcs);

    k_gemm<<<(NN + 31) / 32, 256, 0, stream>>>(feat, W, ft, NN);
    k_agg<<<NN / 4, 256, 0, stream>>>((const float2*)ft, row, srcs, (float2*)out);
}

// Round 6
// 290.213 us; speedup vs baseline: 2.4195x; 1.1522x over previous
//
#include <hip/hip_runtime.h>
#include <math.h>

#define NN 50000
#define NE 800000
#define HH 4
#define DD 32

// ---------------- GEMM: ft[n,o] = sum_k feat[n,k] * W[o,k] ----------------
// Block: 64 rows x 128 cols, 256 threads, thread tile 4 rows x 8 cols.
// K tiled in chunks of 32. LDS ~26 KB -> 3+ blocks/CU (12+ waves).
__global__ __launch_bounds__(256) void k_gemm(const float* __restrict__ feat,
                                              const float* __restrict__ W,
                                              float* __restrict__ ft, int N) {
    __shared__ float Wt[32][132];  // Wt[k][o] = W[o][kc+k]; 132: rows 16B-aligned
    __shared__ float fs[64][36];   // fs[r][k]; 36: 16B-aligned rows, stride-4 banks

    int tid = threadIdx.x;
    int row0 = blockIdx.x * 64;
    int cl = tid & 15;   // cols 8*cl .. 8*cl+7
    int rg = tid >> 4;   // rows rg, rg+16, rg+32, rg+48

    float acc[4][8];
#pragma unroll
    for (int t = 0; t < 4; ++t)
#pragma unroll
        for (int j = 0; j < 8; ++j) acc[t][j] = 0.f;

    for (int kc = 0; kc < 128; kc += 32) {
        __syncthreads();
        // stage W chunk (coalesced: consecutive tid -> consecutive k)
#pragma unroll
        for (int i = tid; i < 32 * 128; i += 256) {
            int k = i & 31, o = i >> 5;
            Wt[k][o] = W[o * 128 + kc + k];
        }
        // stage feat chunk
#pragma unroll
        for (int i = tid; i < 64 * 32; i += 256) {
            int k = i & 31, r = i >> 5;
            int gr = row0 + r;
            fs[r][k] = (gr < N) ? feat[(size_t)gr * 128 + kc + k] : 0.f;
        }
        __syncthreads();

#pragma unroll
        for (int k4 = 0; k4 < 32; k4 += 4) {
            float fk[4][4];
#pragma unroll
            for (int t = 0; t < 4; ++t) {
                float4 fq = *(const float4*)&fs[rg + 16 * t][k4];
                fk[t][0] = fq.x; fk[t][1] = fq.y; fk[t][2] = fq.z; fk[t][3] = fq.w;
            }
#pragma unroll
            for (int kk = 0; kk < 4; ++kk) {
                float4 w0 = *(const float4*)&Wt[k4 + kk][cl * 8];
                float4 w1 = *(const float4*)&Wt[k4 + kk][cl * 8 + 4];
                float wv[8] = {w0.x, w0.y, w0.z, w0.w, w1.x, w1.y, w1.z, w1.w};
#pragma unroll
                for (int t = 0; t < 4; ++t) {
                    float f = fk[t][kk];
#pragma unroll
                    for (int j = 0; j < 8; ++j) acc[t][j] += f * wv[j];
                }
            }
        }
    }

#pragma unroll
    for (int t = 0; t < 4; ++t) {
        int g = row0 + rg + 16 * t;
        if (g < N) {
            *(float4*)&ft[(size_t)g * 128 + cl * 8] =
                make_float4(acc[t][0], acc[t][1], acc[t][2], acc[t][3]);
            *(float4*)&ft[(size_t)g * 128 + cl * 8 + 4] =
                make_float4(acc[t][4], acc[t][5], acc[t][6], acc[t][7]);
        }
    }
}

// ---------------- CSR build ----------------
__global__ __launch_bounds__(256) void k_hist(const int* __restrict__ dst, int* __restrict__ cnt) {
    int e = blockIdx.x * 256 + threadIdx.x;
    if (e < NE) atomicAdd(&cnt[dst[e]], 1);
}

__global__ __launch_bounds__(256) void k_scan1(const int* __restrict__ cnt, int* __restrict__ row,
                                               int* __restrict__ partial, int n) {
    __shared__ int sh[256];
    int i = blockIdx.x * 256 + threadIdx.x;
    int x = (i < n) ? cnt[i] : 0;
    sh[threadIdx.x] = x;
    __syncthreads();
    for (int off = 1; off < 256; off <<= 1) {
        int v = (threadIdx.x >= off) ? sh[threadIdx.x - off] : 0;
        __syncthreads();
        sh[threadIdx.x] += v;
        __syncthreads();
    }
    if (i < n) row[i] = sh[threadIdx.x] - x;  // exclusive
    if (threadIdx.x == 255) partial[blockIdx.x] = sh[255];
}

__global__ __launch_bounds__(256) void k_scan2(int* __restrict__ partial, int nb) {
    __shared__ int sh[256];
    int t = threadIdx.x;
    int x = (t < nb) ? partial[t] : 0;
    sh[t] = x;
    __syncthreads();
    for (int off = 1; off < 256; off <<= 1) {
        int v = (t >= off) ? sh[t - off] : 0;
        __syncthreads();
        sh[t] += v;
        __syncthreads();
    }
    if (t < nb) partial[t] = sh[t] - x;  // exclusive block offsets
}

__global__ __launch_bounds__(256) void k_scan3(int* __restrict__ row, int* __restrict__ cur,
                                               const int* __restrict__ partial, int n) {
    int i = blockIdx.x * 256 + threadIdx.x;
    if (i < n) {
        int val = row[i] + partial[blockIdx.x];
        row[i] = val;
        cur[i] = val;
    }
    if (i == 0) row[n] = NE;
}

__global__ __launch_bounds__(256) void k_fill(const int* __restrict__ src, const int* __restrict__ dst,
                                              int* __restrict__ cur, int* __restrict__ srcs) {
    int e = blockIdx.x * 256 + threadIdx.x;
    if (e >= NE) return;
    int p = atomicAdd(&cur[dst[e]], 1);
    srcs[p] = src[e];
}

// ---------------- fused edge-dot + online softmax + aggregate ----------------
// one WAVE (64 lanes) per dst node; lane l owns channels 2l,2l+1 (float2).
// Head group = 16 lanes; per-head dot via 4x shfl_xor. Edges processed in
// pairs: two independent shuffle chains (ILP) + single online rescale/pair.
__global__ __launch_bounds__(256) void k_agg(const float2* __restrict__ ft2,
                                             const int* __restrict__ row,
                                             const int* __restrict__ srcs,
                                             float2* __restrict__ out2) {
    int n = blockIdx.x * 4 + (threadIdx.x >> 6);
    int l = threadIdx.x & 63;
    int r0 = row[n], r1 = row[n + 1];
    size_t base = (size_t)n * 64 + l;
    float2 fd = ft2[base];  // dst row, loaded once
    float m = -INFINITY, s = 0.f;
    float ax = 0.f, ay = 0.f;
    int p = r0;
    for (; p + 1 < r1; p += 2) {
        int s0 = srcs[p], s1 = srcs[p + 1];
        float2 f0 = ft2[(size_t)s0 * 64 + l];
        float2 f1 = ft2[(size_t)s1 * 64 + l];
        float v0 = fd.x * f0.x + fd.y * f0.y;
        float v1 = fd.x * f1.x + fd.y * f1.y;
        v0 += __shfl_xor(v0, 1);  v1 += __shfl_xor(v1, 1);
        v0 += __shfl_xor(v0, 2);  v1 += __shfl_xor(v1, 2);
        v0 += __shfl_xor(v0, 4);  v1 += __shfl_xor(v1, 4);
        v0 += __shfl_xor(v0, 8);  v1 += __shfl_xor(v1, 8);
        v0 *= 0.17677669529663687f;  // 1/sqrt(32)
        v1 *= 0.17677669529663687f;
        float mn = fmaxf(fmaxf(m, v0), v1);  // v_max3
        float sc = __expf(m - mn);           // 0 on first pair (m=-inf)
        float w0 = __expf(v0 - mn);
        float w1 = __expf(v1 - mn);
        s = s * sc + w0 + w1;
        ax = ax * sc + w0 * f0.x + w1 * f1.x;
        ay = ay * sc + w0 * f0.y + w1 * f1.y;
        m = mn;
    }
    if (p < r1) {  // odd tail
        int s0 = srcs[p];
        float2 f0 = ft2[(size_t)s0 * 64 + l];
        float v0 = fd.x * f0.x + fd.y * f0.y;
        v0 += __shfl_xor(v0, 1);
        v0 += __shfl_xor(v0, 2);
        v0 += __shfl_xor(v0, 4);
        v0 += __shfl_xor(v0, 8);
        v0 *= 0.17677669529663687f;
        float mn = fmaxf(m, v0);
        float sc = __expf(m - mn);
        float w0 = __expf(v0 - mn);
        s = s * sc + w0;
        ax = ax * sc + w0 * f0.x;
        ay = ay * sc + w0 * f0.y;
    }
    float inv = (r1 > r0) ? 1.f / s : 0.f;
    out2[base] = make_float2(ax * inv, ay * inv);
}

extern "C" void kernel_launch(void* const* d_in, const int* in_sizes, int n_in,
                              void* d_out, int out_size, void* d_ws, size_t ws_size,
                              hipStream_t stream) {
    const float* feat = (const float*)d_in[0];
    const float* W    = (const float*)d_in[1];
    const int*   src  = (const int*)d_in[2];
    const int*   dst  = (const int*)d_in[3];
    float* out = (float*)d_out;

    // workspace layout (4-byte units)
    float* ft   = (float*)d_ws;                 // 6,400,000
    int*   row  = (int*)(ft + (size_t)NN * 128);// 50,001
    int*   cur  = row + (NN + 1);               // 50,000
    int*   srcs = cur + NN;                     // 800,000
    int*   cnt  = srcs + NE;                    // 50,000
    int*   part = cnt + NN;                     // 256

    const int NB1 = (NN + 255) / 256;  // 196

    hipMemsetAsync(cnt, 0, (size_t)NN * sizeof(int), stream);
    k_hist<<<(NE + 255) / 256, 256, 0, stream>>>(dst, cnt);
    k_scan1<<<NB1, 256, 0, stream>>>(cnt, row, part, NN);
    k_scan2<<<1, 256, 0, stream>>>(part, NB1);
    k_scan3<<<NB1, 256, 0, stream>>>(row, cur, part, NN);
    k_fill<<<(NE + 255) / 256, 256, 0, stream>>>(src, dst, cur, srcs);

    k_gemm<<<(NN + 63) / 64, 256, 0, stream>>>(feat, W, ft, NN);
    k_agg<<<NN / 4, 256, 0, stream>>>((const float2*)ft, row, srcs, (float2*)out);
}

// Round 7
// 259.991 us; speedup vs baseline: 2.7008x; 1.1162x over previous
//
#include <hip/hip_runtime.h>
#include <math.h>

#define NN 50000
#define NE 800000
#define HH 4
#define DD 32

typedef __attribute__((ext_vector_type(8))) short short8;
typedef __attribute__((ext_vector_type(4))) float f32x4;

__device__ __forceinline__ unsigned short f2bf(float x) {
    unsigned u = __float_as_uint(x);
    unsigned r = (u + 0x7FFF + ((u >> 16) & 1)) >> 16;  // RNE
    return (unsigned short)r;
}

__device__ __forceinline__ short8 pack8(float4 p, float4 q) {
    short8 r;
    r[0] = (short)f2bf(p.x); r[1] = (short)f2bf(p.y);
    r[2] = (short)f2bf(p.z); r[3] = (short)f2bf(p.w);
    r[4] = (short)f2bf(q.x); r[5] = (short)f2bf(q.y);
    r[6] = (short)f2bf(q.z); r[7] = (short)f2bf(q.w);
    return r;
}

// ---------------- MFMA GEMM: ft[n,o] = sum_k feat[n,k] * W[o,k] ----------------
// 256 thr = 4 waves; 64 rows/block; W staged fragment-major bf16 in LDS.
// mfma_f32_16x16x32_bf16: A row=l&15,k=(l>>4)*8+e; B col=l&15,k=(l>>4)*8+e;
// D col=l&15,row=(l>>4)*4+reg (m89-verified).
__global__ __launch_bounds__(256) void k_gemm(const float* __restrict__ feat,
                                              const float* __restrict__ W,
                                              float* __restrict__ ft, int N) {
    __shared__ short8 wlds[2048];  // [kc][ct][lane] -> 16B frag; 32 KB

    int tid = threadIdx.x;
    // stage W frag-major: frag f: kc=f>>9, ct=(f>>6)&7, l=f&63
#pragma unroll
    for (int j = 0; j < 8; ++j) {
        int f = tid + j * 256;
        int kc = f >> 9, ct = (f >> 6) & 7, l = f & 63;
        int o = ct * 16 + (l & 15);
        int kb = kc * 32 + ((l >> 4) << 3);
        const float* wp = W + o * 128 + kb;
        float4 p = *(const float4*)wp;
        float4 q = *(const float4*)(wp + 4);
        wlds[f] = pack8(p, q);
    }
    __syncthreads();

    int l = tid & 63;
    int w = tid >> 6;
    int row0 = blockIdx.x * 64;
    int arow = row0 + w * 16 + (l & 15);
    bool valid = arow < N;
    const float* fb = feat + (size_t)(valid ? arow : 0) * 128 + ((l >> 4) << 3);

    f32x4 acc[8];
#pragma unroll
    for (int ct = 0; ct < 8; ++ct) acc[ct] = (f32x4){0.f, 0.f, 0.f, 0.f};

#pragma unroll
    for (int kc = 0; kc < 4; ++kc) {
        short8 a;
        if (valid) {
            float4 p = *(const float4*)(fb + kc * 32);
            float4 q = *(const float4*)(fb + kc * 32 + 4);
            a = pack8(p, q);
        } else {
            a = (short8){0, 0, 0, 0, 0, 0, 0, 0};
        }
#pragma unroll
        for (int ct = 0; ct < 8; ++ct) {
            short8 b = wlds[kc * 512 + ct * 64 + l];
            acc[ct] = __builtin_amdgcn_mfma_f32_16x16x32_bf16(a, b, acc[ct], 0, 0, 0);
        }
    }

    int oc = l & 15;
    int rg = l >> 4;
#pragma unroll
    for (int i = 0; i < 4; ++i) {
        int r = row0 + w * 16 + rg * 4 + i;
        if (r < N) {
            float* op = ft + (size_t)r * 128 + oc;
#pragma unroll
            for (int ct = 0; ct < 8; ++ct) op[ct * 16] = acc[ct][i];
        }
    }
}

// ---------------- CSR build ----------------
__global__ __launch_bounds__(256) void k_hist(const int* __restrict__ dst, int* __restrict__ cnt) {
    int e = blockIdx.x * 256 + threadIdx.x;
    if (e < NE) atomicAdd(&cnt[dst[e]], 1);
}

__global__ __launch_bounds__(256) void k_scan1(const int* __restrict__ cnt, int* __restrict__ row,
                                               int* __restrict__ partial, int n) {
    __shared__ int sh[256];
    int i = blockIdx.x * 256 + threadIdx.x;
    int x = (i < n) ? cnt[i] : 0;
    sh[threadIdx.x] = x;
    __syncthreads();
    for (int off = 1; off < 256; off <<= 1) {
        int v = (threadIdx.x >= off) ? sh[threadIdx.x - off] : 0;
        __syncthreads();
        sh[threadIdx.x] += v;
        __syncthreads();
    }
    if (i < n) row[i] = sh[threadIdx.x] - x;  // exclusive
    if (threadIdx.x == 255) partial[blockIdx.x] = sh[255];
}

__global__ __launch_bounds__(256) void k_scan2(int* __restrict__ partial, int nb) {
    __shared__ int sh[256];
    int t = threadIdx.x;
    int x = (t < nb) ? partial[t] : 0;
    sh[t] = x;
    __syncthreads();
    for (int off = 1; off < 256; off <<= 1) {
        int v = (t >= off) ? sh[t - off] : 0;
        __syncthreads();
        sh[t] += v;
        __syncthreads();
    }
    if (t < nb) partial[t] = sh[t] - x;  // exclusive block offsets
}

__global__ __launch_bounds__(256) void k_scan3(int* __restrict__ row, int* __restrict__ cur,
                                               const int* __restrict__ partial, int n) {
    int i = blockIdx.x * 256 + threadIdx.x;
    if (i < n) {
        int val = row[i] + partial[blockIdx.x];
        row[i] = val;
        cur[i] = val;
    }
    if (i == 0) row[n] = NE;
}

__global__ __launch_bounds__(256) void k_fill(const int* __restrict__ src, const int* __restrict__ dst,
                                              int* __restrict__ cur, int* __restrict__ srcs) {
    int e = blockIdx.x * 256 + threadIdx.x;
    if (e >= NE) return;
    int p = atomicAdd(&cur[dst[e]], 1);
    srcs[p] = src[e];
}

// ---------------- fused edge-dot + online softmax + aggregate ----------------
// one WAVE (64 lanes) per dst node; lane l owns channels 2l,2l+1 (float2).
// Head group = 16 lanes; per-head dot via 4x shfl_xor. Edges processed in
// pairs: two independent shuffle chains (ILP) + single online rescale/pair.
__global__ __launch_bounds__(256) void k_agg(const float2* __restrict__ ft2,
                                             const int* __restrict__ row,
                                             const int* __restrict__ srcs,
                                             float2* __restrict__ out2) {
    int n = blockIdx.x * 4 + (threadIdx.x >> 6);
    int l = threadIdx.x & 63;
    int r0 = row[n], r1 = row[n + 1];
    size_t base = (size_t)n * 64 + l;
    float2 fd = ft2[base];  // dst row, loaded once
    float m = -INFINITY, s = 0.f;
    float ax = 0.f, ay = 0.f;
    int p = r0;
    for (; p + 1 < r1; p += 2) {
        int s0 = srcs[p], s1 = srcs[p + 1];
        float2 f0 = ft2[(size_t)s0 * 64 + l];
        float2 f1 = ft2[(size_t)s1 * 64 + l];
        float v0 = fd.x * f0.x + fd.y * f0.y;
        float v1 = fd.x * f1.x + fd.y * f1.y;
        v0 += __shfl_xor(v0, 1);  v1 += __shfl_xor(v1, 1);
        v0 += __shfl_xor(v0, 2);  v1 += __shfl_xor(v1, 2);
        v0 += __shfl_xor(v0, 4);  v1 += __shfl_xor(v1, 4);
        v0 += __shfl_xor(v0, 8);  v1 += __shfl_xor(v1, 8);
        v0 *= 0.17677669529663687f;  // 1/sqrt(32)
        v1 *= 0.17677669529663687f;
        float mn = fmaxf(fmaxf(m, v0), v1);  // v_max3
        float sc = __expf(m - mn);           // 0 on first pair (m=-inf)
        float w0 = __expf(v0 - mn);
        float w1 = __expf(v1 - mn);
        s = s * sc + w0 + w1;
        ax = ax * sc + w0 * f0.x + w1 * f1.x;
        ay = ay * sc + w0 * f0.y + w1 * f1.y;
        m = mn;
    }
    if (p < r1) {  // odd tail
        int s0 = srcs[p];
        float2 f0 = ft2[(size_t)s0 * 64 + l];
        float v0 = fd.x * f0.x + fd.y * f0.y;
        v0 += __shfl_xor(v0, 1);
        v0 += __shfl_xor(v0, 2);
        v0 += __shfl_xor(v0, 4);
        v0 += __shfl_xor(v0, 8);
        v0 *= 0.17677669529663687f;
        float mn = fmaxf(m, v0);
        float sc = __expf(m - mn);
        float w0 = __expf(v0 - mn);
        s = s * sc + w0;
        ax = ax * sc + w0 * f0.x;
        ay = ay * sc + w0 * f0.y;
    }
    float inv = (r1 > r0) ? 1.f / s : 0.f;
    out2[base] = make_float2(ax * inv, ay * inv);
}

extern "C" void kernel_launch(void* const* d_in, const int* in_sizes, int n_in,
                              void* d_out, int out_size, void* d_ws, size_t ws_size,
                              hipStream_t stream) {
    const float* feat = (const float*)d_in[0];
    const float* W    = (const float*)d_in[1];
    const int*   src  = (const int*)d_in[2];
    const int*   dst  = (const int*)d_in[3];
    float* out = (float*)d_out;

    // workspace layout (4-byte units)
    float* ft   = (float*)d_ws;                 // 6,400,000
    int*   row  = (int*)(ft + (size_t)NN * 128);// 50,001
    int*   cur  = row + (NN + 1);               // 50,000
    int*   srcs = cur + NN;                     // 800,000
    int*   cnt  = srcs + NE;                    // 50,000
    int*   part = cnt + NN;                     // 256

    const int NB1 = (NN + 255) / 256;  // 196

    hipMemsetAsync(cnt, 0, (size_t)NN * sizeof(int), stream);
    k_hist<<<(NE + 255) / 256, 256, 0, stream>>>(dst, cnt);
    k_scan1<<<NB1, 256, 0, stream>>>(cnt, row, part, NN);
    k_scan2<<<1, 256, 0, stream>>>(part, NB1);
    k_scan3<<<NB1, 256, 0, stream>>>(row, cur, part, NN);
    k_fill<<<(NE + 255) / 256, 256, 0, stream>>>(src, dst, cur, srcs);

    k_gemm<<<(NN + 63) / 64, 256, 0, stream>>>(feat, W, ft, NN);
    k_agg<<<NN / 4, 256, 0, stream>>>((const float2*)ft, row, srcs, (float2*)out);
}